// Round 8
// baseline (312.325 us; speedup 1.0000x reference)
//
#include <hip/hip_runtime.h>

static constexpr int BATCH = 16;
static constexpr int NNODE = 4096;
static constexpr int NEDGE = 65536;            // 1 << 16
static constexpr int ROWS  = BATCH * NNODE;    // 65536

typedef _Float16 half8  __attribute__((ext_vector_type(8)));
typedef _Float16 half4v __attribute__((ext_vector_type(4)));
typedef _Float16 half2v __attribute__((ext_vector_type(2)));
typedef float    f32x4  __attribute__((ext_vector_type(4)));
typedef float    f32x2  __attribute__((ext_vector_type(2)));

template<typename T, int N> struct VT;
template<> struct VT<_Float16, 4> { using type = half4v; };
template<> struct VT<float, 2>    { using type = f32x2; };

// ---------------- CSR build (once; reused by all 3 layers) ----------------

__global__ __launch_bounds__(256) void count_kernel(
    const int* __restrict__ ei, const int* __restrict__ mask,
    int* __restrict__ counts)
{
    const int idx = blockIdx.x * 256 + threadIdx.x;
    const int b = idx >> 16;
    const int e = idx & (NEDGE - 1);
    const int* eib = ei + (size_t)b * 2 * NEDGE;
    const int u = eib[e];
    const int v = eib[NEDGE + e];
    const int mrow = b * NNODE;
    if (mask[mrow + u] != 0 && mask[mrow + v] != 0)
        atomicAdd(&counts[mrow + v], 1);
}

__global__ __launch_bounds__(256) void scan_kernel(
    const int* __restrict__ counts, int* __restrict__ row_start,
    int* __restrict__ cursor)
{
    __shared__ int sums[256];
    const int b = blockIdx.x, t = threadIdx.x;
    const int* c = counts + b * NNODE;
    int* rs = row_start + b * (NNODE + 1);
    int* cu = cursor + b * NNODE;

    int local[16]; int s = 0;
    #pragma unroll
    for (int i = 0; i < 16; ++i) { local[i] = c[t * 16 + i]; s += local[i]; }
    sums[t] = s;
    __syncthreads();
    for (int off = 1; off < 256; off <<= 1) {
        int v = (t >= off) ? sums[t - off] : 0;
        __syncthreads();
        sums[t] += v;
        __syncthreads();
    }
    int run = (t == 0) ? 0 : sums[t - 1];
    #pragma unroll
    for (int i = 0; i < 16; ++i) { rs[t * 16 + i] = run; cu[t * 16 + i] = run; run += local[i]; }
    if (t == 255) rs[NNODE] = run;
}

// bkt[b][pos] = (fp16bits(w) << 16) | u
__global__ __launch_bounds__(256) void fill_kernel(
    const int* __restrict__ ei, const float* __restrict__ ew,
    const int* __restrict__ mask, int* __restrict__ cursor,
    unsigned int* __restrict__ bkt)
{
    const int idx = blockIdx.x * 256 + threadIdx.x;
    const int b = idx >> 16;
    const int e = idx & (NEDGE - 1);
    const int* eib = ei + (size_t)b * 2 * NEDGE;
    const int u = eib[e];
    const int v = eib[NEDGE + e];
    const int mrow = b * NNODE;
    if (mask[mrow + u] != 0 && mask[mrow + v] != 0) {
        const _Float16 w = (_Float16)ew[(size_t)b * NEDGE + e];
        const unsigned short wb = __builtin_bit_cast(unsigned short, w);
        const int pos = atomicAdd(&cursor[mrow + v], 1);
        bkt[(size_t)b * NEDGE + pos] = ((unsigned)wb << 16) | (unsigned)u;
    }
}

// W [K][Nd] fp32 -> Wt [Nd][K] fp16
__global__ __launch_bounds__(256) void wt_kernel(
    const float* __restrict__ W, _Float16* __restrict__ Wt, int K, int Nd)
{
    int i = blockIdx.x * 256 + threadIdx.x;
    if (i < K * Nd) {
        int k = i / Nd, n = i - k * Nd;
        Wt[n * K + k] = (_Float16)W[i];
    }
}

// ---------------- fused layer: Out = relu( (S . Xin) @ Wt^T + b ) * mask ----
// Block = 64 destination rows.
//  phase1: gather rows into LDS (fp32 acc -> fp16), 16 nodes/wave, 8-deep MLP
//  phase2: barrier-free MFMA k-loop: A from LDS, B frags direct from global Wt
//  phase3: epilogue (bias+relu+mask) restaged through LDS, coalesced stores
template<int K, int ND, typename IT, typename OT>
__global__ __launch_bounds__(256, 3) void fused_layer(
    const IT* __restrict__ Xin,        // [ROWS, K]
    const _Float16* __restrict__ Wt,   // [ND, K]
    const int* __restrict__ row_start, const unsigned int* __restrict__ bkt,
    const int* __restrict__ mask, const float* __restrict__ bias,
    OT* __restrict__ Out)              // [ROWS, ND]
{
    constexpr int PER  = K / 64;          // input elems/lane (2 fp32 | 4 fp16)
    constexpr int SSTR = K + 8;           // gather LDS stride (halfs): +16B -> bank shift 4
    constexpr int WC   = (ND == 256) ? 4 : 2;   // waves across cols
    constexpr int MI   = (WC == 4) ? 4 : 2;     // 16-row tiles per wave
    constexpr int NI   = 4;                     // 16-col tiles per wave
    using ivec = typename VT<IT, PER>::type;

    __shared__ __align__(16) char lds_raw[33792];  // covers gather A and restage
    _Float16* A16 = (_Float16*)lds_raw;

    const int tid  = threadIdx.x;
    const int lane = tid & 63;
    const int wave = tid >> 6;
    const int bm   = blockIdx.x * 64;     // global row base (one batch per block)
    const int b    = bm >> 12;
    const int nb   = bm & (NNODE - 1);

    // ---- phase 1: gather ----
    const int* rs = row_start + b * (NNODE + 1) + nb;
    const unsigned* bk = bkt + (size_t)b * NEDGE;
    const IT* Xb = Xin + (size_t)b * NNODE * K + lane * PER;

    for (int j = 0; j < 16; ++j) {
        const int n = wave * 16 + j;
        const int s = rs[n], e = rs[n + 1];
        float acc[PER] = {};
        for (int i = s; i < e; i += 8) {
            const int cnt = e - i;   // >= 1
            unsigned pk[8];
            #pragma unroll
            for (int t = 0; t < 8; ++t) pk[t] = bk[i + t];  // slack-safe over-read
            const unsigned uu0 = pk[0] & 0xffffu;
            float wj[8]; const IT* hp[8];
            #pragma unroll
            for (int t = 0; t < 8; ++t) {
                const bool ok = (t < cnt);
                const unsigned u = ok ? (pk[t] & 0xffffu) : uu0;
                wj[t] = ok ? (float)__builtin_bit_cast(_Float16, (unsigned short)(pk[t] >> 16)) : 0.0f;
                hp[t] = Xb + (size_t)u * K;
            }
            ivec hv[8];
            #pragma unroll
            for (int t = 0; t < 8; ++t) hv[t] = *(const ivec*)hp[t];
            #pragma unroll
            for (int t = 0; t < 8; ++t)
                #pragma unroll
                for (int c = 0; c < PER; ++c) acc[c] += wj[t] * (float)hv[t][c];
        }
        if constexpr (PER == 2) {
            half2v o = {(_Float16)acc[0], (_Float16)acc[1]};
            *(half2v*)&A16[n * SSTR + lane * 2] = o;
        } else {
            half4v o = {(_Float16)acc[0], (_Float16)acc[1], (_Float16)acc[2], (_Float16)acc[3]};
            *(half4v*)&A16[n * SSTR + lane * 4] = o;
        }
    }
    __syncthreads();

    // ---- phase 2: MFMA (no barriers in the k-loop) ----
    const int waveC = wave % WC;
    const int waveR = wave / WC;
    const int quad  = lane >> 4;
    const int l15   = lane & 15;

    f32x4 acc[MI][NI];
    #pragma unroll
    for (int mi = 0; mi < MI; ++mi)
        #pragma unroll
        for (int ni = 0; ni < NI; ++ni) acc[mi][ni] = (f32x4)0.0f;

    const _Float16* ap = A16 + (waveR * (MI * 16) + l15) * SSTR + quad * 8;
    const _Float16* wp = Wt + (size_t)(waveC * (NI * 16) + l15) * K + quad * 8;

    #pragma unroll
    for (int k0 = 0; k0 < K; k0 += 32) {
        half8 af[MI], bf[NI];
        #pragma unroll
        for (int mi = 0; mi < MI; ++mi)
            af[mi] = *(const half8*)(ap + mi * 16 * SSTR + k0);
        #pragma unroll
        for (int ni = 0; ni < NI; ++ni)
            bf[ni] = *(const half8*)(wp + (size_t)ni * 16 * K + k0);
        #pragma unroll
        for (int mi = 0; mi < MI; ++mi)
            #pragma unroll
            for (int ni = 0; ni < NI; ++ni)
                acc[mi][ni] = __builtin_amdgcn_mfma_f32_16x16x32_f16(
                    bf[ni], af[mi], acc[mi][ni], 0, 0, 0);   // swapped operands
    }
    __syncthreads();   // A16 now free for restage

    // ---- phase 3: epilogue ----
    // lane holds (row = rowBase + mi*16 + l15, cols = colBase + ni*16 + quad*4 .. +3)
    const int rowBase = waveR * (MI * 16);
    const int colBase = waveC * (NI * 16);
    if constexpr (sizeof(OT) == 2) {
        constexpr int RSTR = ND + 8;
        _Float16* S16 = (_Float16*)lds_raw;
        #pragma unroll
        for (int mi = 0; mi < MI; ++mi) {
            const int row = rowBase + mi * 16 + l15;
            const bool ok = (mask[bm + row] != 0);
            #pragma unroll
            for (int ni = 0; ni < NI; ++ni) {
                const int col = colBase + ni * 16 + quad * 4;
                f32x4 v = acc[mi][ni];
                half4v o;
                #pragma unroll
                for (int r = 0; r < 4; ++r)
                    o[r] = (_Float16)(ok ? fmaxf(v[r] + bias[col + r], 0.0f) : 0.0f);
                *(half4v*)&S16[row * RSTR + col] = o;
            }
        }
        __syncthreads();
        constexpr int CH = ND / 8;      // half8 chunks per row
        for (int i = tid; i < 64 * CH; i += 256) {
            const int row = i / CH, ch = i - row * CH;
            half8 v = *(const half8*)&S16[row * RSTR + ch * 8];
            *(half8*)&Out[(size_t)(bm + row) * ND + ch * 8] = v;
        }
    } else {
        constexpr int RSTRF = ND + 4;   // float stride
        float* S32 = (float*)lds_raw;
        #pragma unroll
        for (int mi = 0; mi < MI; ++mi) {
            const int row = rowBase + mi * 16 + l15;
            const bool ok = (mask[bm + row] != 0);
            #pragma unroll
            for (int ni = 0; ni < NI; ++ni) {
                const int col = colBase + ni * 16 + quad * 4;
                f32x4 v = acc[mi][ni];
                f32x4 o;
                #pragma unroll
                for (int r = 0; r < 4; ++r)
                    o[r] = ok ? fmaxf(v[r] + bias[col + r], 0.0f) : 0.0f;
                *(f32x4*)&S32[row * RSTRF + col] = o;
            }
        }
        __syncthreads();
        constexpr int CHF = ND / 4;     // f32x4 chunks per row
        for (int i = tid; i < 64 * CHF; i += 256) {
            const int row = i / CHF, ch = i - row * CHF;
            f32x4 v = *(const f32x4*)&S32[row * RSTRF + ch * 4];
            *(f32x4*)&Out[(size_t)(bm + row) * ND + ch * 4] = v;
        }
    }
}

extern "C" void kernel_launch(void* const* d_in, const int* in_sizes, int n_in,
                              void* d_out, int out_size, void* d_ws, size_t ws_size,
                              hipStream_t stream) {
    const float* x    = (const float*)d_in[0];
    const int*   ei   = (const int*)  d_in[1];
    const float* ew   = (const float*)d_in[2];
    const int*   mask = (const int*)  d_in[3];
    const float* W1   = (const float*)d_in[4];
    const float* b1   = (const float*)d_in[5];
    const float* W2   = (const float*)d_in[6];
    const float* b2   = (const float*)d_in[7];
    const float* W3   = (const float*)d_in[8];
    const float* b3   = (const float*)d_in[9];
    float* out = (float*)d_out;

    // Workspace layout (~69 MB):
    char* ws = (char*)d_ws;
    _Float16* O1 = (_Float16*)(ws);                                   // 32 MB [65536x256]
    _Float16* O2 = (_Float16*)(ws + (32u << 20));                     // 32 MB [65536x256]
    unsigned int* bkt = (unsigned int*)(ws + (64u << 20));            // 4 MB
    _Float16* Wt1  = (_Float16*)(ws + (68u << 20));                   // 64 KB  [256][128]
    _Float16* Wt2  = Wt1 + 128 * 256;                                 // 128 KB [256][256]
    _Float16* Wt3  = Wt2 + 256 * 256;                                 // 64 KB  [128][256]
    int* counts    = (int*)(Wt3 + 256 * 128);
    int* row_start = counts + BATCH * NNODE;
    int* cursor    = row_start + BATCH * (NNODE + 1);

    const dim3 blk(256);
    const int edgeBlocks  = BATCH * NEDGE / 256;   // 4096
    const int layerBlocks = ROWS / 64;             // 1024

    // ---- CSR build (layer-invariant) ----
    hipMemsetAsync(counts, 0, (size_t)BATCH * NNODE * sizeof(int), stream);
    count_kernel<<<edgeBlocks, blk, 0, stream>>>(ei, mask, counts);
    scan_kernel<<<BATCH, blk, 0, stream>>>(counts, row_start, cursor);
    fill_kernel<<<edgeBlocks, blk, 0, stream>>>(ei, ew, mask, cursor, bkt);

    // ---- weight transpose+cast ----
    wt_kernel<<<(128 * 256 + 255) / 256, blk, 0, stream>>>(W1, Wt1, 128, 256);
    wt_kernel<<<(256 * 256 + 255) / 256, blk, 0, stream>>>(W2, Wt2, 256, 256);
    wt_kernel<<<(256 * 128 + 255) / 256, blk, 0, stream>>>(W3, Wt3, 256, 128);

    // ---- Layer 1: O1 = relu( (S x) @ W1 + b1 ) * mask ----
    fused_layer<128, 256, float, _Float16><<<layerBlocks, blk, 0, stream>>>(
        x, Wt1, row_start, bkt, mask, b1, O1);

    // ---- Layer 2: O2 = relu( (S O1) @ W2 + b2 ) * mask ----
    fused_layer<256, 256, _Float16, _Float16><<<layerBlocks, blk, 0, stream>>>(
        O1, Wt2, row_start, bkt, mask, b2, O2);

    // ---- Layer 3: out = relu( (S O2) @ W3 + b3 ) * mask ----
    fused_layer<256, 128, _Float16, float><<<layerBlocks, blk, 0, stream>>>(
        O2, Wt3, row_start, bkt, mask, b3, out);
}

// Round 9
// 261.347 us; speedup vs baseline: 1.1951x; 1.1951x over previous
//
#include <hip/hip_runtime.h>

static constexpr int BATCH = 16;
static constexpr int NNODE = 4096;
static constexpr int NEDGE = 65536;            // 1 << 16
static constexpr int ROWS  = BATCH * NNODE;    // 65536

typedef _Float16 half8  __attribute__((ext_vector_type(8)));
typedef _Float16 half4v __attribute__((ext_vector_type(4)));
typedef _Float16 half2v __attribute__((ext_vector_type(2)));
typedef float    f32x4  __attribute__((ext_vector_type(4)));
typedef float    f32x2  __attribute__((ext_vector_type(2)));

template<typename T, int N> struct VT;
template<> struct VT<_Float16, 2> { using type = half2v; };
template<> struct VT<_Float16, 4> { using type = half4v; };
template<> struct VT<float, 2>    { using type = f32x2; };
template<> struct VT<float, 4>    { using type = f32x4; };

// ---------------- CSR build (once; reused by all 3 layers) ----------------

__global__ __launch_bounds__(256) void count_kernel(
    const int* __restrict__ ei, const int* __restrict__ mask,
    int* __restrict__ counts)
{
    const int idx = blockIdx.x * 256 + threadIdx.x;
    const int b = idx >> 16;
    const int e = idx & (NEDGE - 1);
    const int* eib = ei + (size_t)b * 2 * NEDGE;
    const int u = eib[e];
    const int v = eib[NEDGE + e];
    const int mrow = b * NNODE;
    if (mask[mrow + u] != 0 && mask[mrow + v] != 0)
        atomicAdd(&counts[mrow + v], 1);
}

__global__ __launch_bounds__(256) void scan_kernel(
    const int* __restrict__ counts, int* __restrict__ row_start,
    int* __restrict__ cursor)
{
    __shared__ int sums[256];
    const int b = blockIdx.x, t = threadIdx.x;
    const int* c = counts + b * NNODE;
    int* rs = row_start + b * (NNODE + 1);
    int* cu = cursor + b * NNODE;

    int local[16]; int s = 0;
    #pragma unroll
    for (int i = 0; i < 16; ++i) { local[i] = c[t * 16 + i]; s += local[i]; }
    sums[t] = s;
    __syncthreads();
    for (int off = 1; off < 256; off <<= 1) {
        int v = (t >= off) ? sums[t - off] : 0;
        __syncthreads();
        sums[t] += v;
        __syncthreads();
    }
    int run = (t == 0) ? 0 : sums[t - 1];
    #pragma unroll
    for (int i = 0; i < 16; ++i) { rs[t * 16 + i] = run; cu[t * 16 + i] = run; run += local[i]; }
    if (t == 255) rs[NNODE] = run;
}

// bkt[b][pos] = (fp16bits(w) << 16) | u   (u < 4096 fits easily)
__global__ __launch_bounds__(256) void fill_kernel(
    const int* __restrict__ ei, const float* __restrict__ ew,
    const int* __restrict__ mask, int* __restrict__ cursor,
    unsigned int* __restrict__ bkt)
{
    const int idx = blockIdx.x * 256 + threadIdx.x;
    const int b = idx >> 16;
    const int e = idx & (NEDGE - 1);
    const int* eib = ei + (size_t)b * 2 * NEDGE;
    const int u = eib[e];
    const int v = eib[NEDGE + e];
    const int mrow = b * NNODE;
    if (mask[mrow + u] != 0 && mask[mrow + v] != 0) {
        const _Float16 w = (_Float16)ew[(size_t)b * NEDGE + e];
        const unsigned short wb = __builtin_bit_cast(unsigned short, w);
        const int pos = atomicAdd(&cursor[mrow + v], 1);
        bkt[(size_t)b * NEDGE + pos] = ((unsigned)wb << 16) | (unsigned)u;
    }
}

// ---------------- dtype prep ----------------

__global__ __launch_bounds__(256) void cast_x_kernel(
    const float* __restrict__ X, _Float16* __restrict__ X16, int n4)
{
    int i = blockIdx.x * 256 + threadIdx.x;
    if (i < n4) {
        float4 v = ((const float4*)X)[i];
        half4v h = {(_Float16)v.x, (_Float16)v.y, (_Float16)v.z, (_Float16)v.w};
        ((half4v*)X16)[i] = h;
    }
}

// W [K][Nd] fp32 -> Wt [Nd][K] fp16
__global__ __launch_bounds__(256) void wt_kernel(
    const float* __restrict__ W, _Float16* __restrict__ Wt, int K, int Nd)
{
    int i = blockIdx.x * 256 + threadIdx.x;
    if (i < K * Nd) {
        int k = i / Nd, n = i - k * Nd;
        Wt[n * K + k] = (_Float16)W[i];
    }
}

// ---------------- H = X @ Wt^T (fp16 in, fp32 acc, fp16 out) ----------------
// 128x128 tile, BK=32, 4 waves of 64x64, operand-swapped mfma (lane holds 4
// consecutive output cols). Epilogue restages through padded LDS (stride 72
// halfs) for fully-coalesced stores: each lane reads TWO half8 chunks
// (16 rows x 8 chunks = 64 lanes x 2 -> full 16x64 coverage).
template<int K>
__global__ __launch_bounds__(256) void gemm_mfma(
    const _Float16* __restrict__ X,   // [M, K]
    const _Float16* __restrict__ Wt,  // [Nd, K]
    _Float16* __restrict__ H,         // [M, Nd]
    int Nd)
{
    __shared__ _Float16 As[128 * 32];     // [m][k]
    __shared__ _Float16 Bs[128 * 32];     // [n][k]
    __shared__ _Float16 stg_all[4 * 16 * 72];  // per-wave 16x64 (+8 pad) restage

    const int tid  = threadIdx.x;
    const int lane = tid & 63;
    const int wave = tid >> 6;
    const int wr = wave >> 1, wc = wave & 1;
    const int quad = lane >> 4;
    const int l15  = lane & 15;

    const size_t bm = (size_t)blockIdx.y * 128;
    const int    bn = blockIdx.x * 128;

    f32x4 acc[4][4] = {};

    const int sr = tid >> 2;
    const int sc = (tid & 3) * 8;
    const _Float16* Ag0 = X  + (bm + sr) * K + sc;
    const _Float16* Ag1 = X  + (bm + 64 + sr) * K + sc;
    const _Float16* Bg0 = Wt + (size_t)(bn + sr) * K + sc;
    const _Float16* Bg1 = Wt + (size_t)(bn + 64 + sr) * K + sc;

    const _Float16* ap = As + (wr * 64 + l15) * 32 + quad * 8;
    const _Float16* bp = Bs + (wc * 64 + l15) * 32 + quad * 8;

    for (int k0 = 0; k0 < K; k0 += 32) {
        __builtin_amdgcn_global_load_lds(
            (const __attribute__((address_space(1))) void*)(Ag0 + k0),
            (__attribute__((address_space(3))) void*)(As + tid * 8), 16, 0, 0);
        __builtin_amdgcn_global_load_lds(
            (const __attribute__((address_space(1))) void*)(Ag1 + k0),
            (__attribute__((address_space(3))) void*)(As + 2048 + tid * 8), 16, 0, 0);
        __builtin_amdgcn_global_load_lds(
            (const __attribute__((address_space(1))) void*)(Bg0 + k0),
            (__attribute__((address_space(3))) void*)(Bs + tid * 8), 16, 0, 0);
        __builtin_amdgcn_global_load_lds(
            (const __attribute__((address_space(1))) void*)(Bg1 + k0),
            (__attribute__((address_space(3))) void*)(Bs + 2048 + tid * 8), 16, 0, 0);
        __syncthreads();

        half8 af[4], bf[4];
        #pragma unroll
        for (int mi = 0; mi < 4; ++mi) af[mi] = *(const half8*)(ap + mi * 16 * 32);
        #pragma unroll
        for (int ni = 0; ni < 4; ++ni) bf[ni] = *(const half8*)(bp + ni * 16 * 32);

        #pragma unroll
        for (int mi = 0; mi < 4; ++mi)
            #pragma unroll
            for (int ni = 0; ni < 4; ++ni)
                acc[mi][ni] = __builtin_amdgcn_mfma_f32_16x16x32_f16(
                    bf[ni], af[mi], acc[mi][ni], 0, 0, 0);   // swapped
        __syncthreads();
    }

    // Epilogue: lane holds rows (l15) x cols (ni*16+quad*4..+3) of its wave's
    // 64x64 tile. Stage 16x64 slices in LDS, read back coalesced, 2x16B/lane.
    _Float16* stg = stg_all + wave * 16 * 72;
    const int rr = lane >> 2;            // readback row (0..15)
    const int cc = (lane & 3) * 8;       // readback col chunks: cc and cc+32
    #pragma unroll
    for (int mi = 0; mi < 4; ++mi) {
        #pragma unroll
        for (int ni = 0; ni < 4; ++ni) {
            f32x4 v = acc[mi][ni];
            half4v o;
            #pragma unroll
            for (int r = 0; r < 4; ++r) o[r] = (_Float16)v[r];
            *(half4v*)&stg[l15 * 72 + ni * 16 + quad * 4] = o;
        }
        half8 v0 = *(const half8*)&stg[rr * 72 + cc];
        half8 v1 = *(const half8*)&stg[rr * 72 + cc + 32];
        const size_t grow = bm + wr * 64 + mi * 16 + rr;
        _Float16* hp = &H[grow * Nd + bn + wc * 64];
        *(half8*)(hp + cc)      = v0;
        *(half8*)(hp + cc + 32) = v1;
    }
}

// ---------------- gather + bias + relu + mask (one wave per node) ----------
// 8-deep edge unroll: 8 independent H-row loads in flight per wave; tail
// clamped to edge 0 with weight 0 (branch-free).
template<int D, typename OT>
__global__ __launch_bounds__(256) void gather_kernel(
    const int* __restrict__ row_start, const unsigned int* __restrict__ bkt,
    const _Float16* __restrict__ H, const int* __restrict__ mask,
    const float* __restrict__ bias, OT* __restrict__ OUT)
{
    constexpr int PER = D / 64;
    using ivec = typename VT<_Float16, PER>::type;
    using ovec = typename VT<OT, PER>::type;

    const int gw   = blockIdx.x * 4 + (threadIdx.x >> 6);
    const int lane = threadIdx.x & 63;
    const int b = gw >> 12;
    const int n = gw & (NNODE - 1);
    const int mrow = b * NNODE + n;

    float acc[PER] = {};
    if (mask[mrow] != 0) {
        const int* rs = row_start + b * (NNODE + 1);
        const int s = rs[n], e = rs[n + 1];
        const unsigned* bk = bkt + (size_t)b * NEDGE;
        const _Float16* Hb = H + (size_t)b * NNODE * D + lane * PER;

        for (int i = s; i < e; i += 8) {
            const int cnt = e - i;   // >= 1
            unsigned pk[8];
            #pragma unroll
            for (int j = 0; j < 8; ++j) pk[j] = bk[i + j];   // slack-safe over-read

            const unsigned u0 = pk[0] & 0xffffu;
            float wj[8];
            const _Float16* hp[8];
            #pragma unroll
            for (int j = 0; j < 8; ++j) {
                const bool ok = (j < cnt);
                const unsigned u = ok ? (pk[j] & 0xffffu) : u0;
                wj[j] = ok ? (float)__builtin_bit_cast(_Float16, (unsigned short)(pk[j] >> 16)) : 0.0f;
                hp[j] = Hb + (size_t)u * D;
            }
            ivec hv[8];
            #pragma unroll
            for (int j = 0; j < 8; ++j) hv[j] = *(const ivec*)hp[j];
            #pragma unroll
            for (int j = 0; j < 8; ++j)
                #pragma unroll
                for (int c = 0; c < PER; ++c) acc[c] += wj[j] * (float)hv[j][c];
        }
        #pragma unroll
        for (int j = 0; j < PER; ++j)
            acc[j] = fmaxf(acc[j] + bias[lane * PER + j], 0.0f);
    }

    ovec o;
    #pragma unroll
    for (int c = 0; c < PER; ++c) o[c] = (OT)acc[c];
    *(ovec*)(OUT + (size_t)mrow * D + lane * PER) = o;
}

extern "C" void kernel_launch(void* const* d_in, const int* in_sizes, int n_in,
                              void* d_out, int out_size, void* d_ws, size_t ws_size,
                              hipStream_t stream) {
    const float* x    = (const float*)d_in[0];
    const int*   ei   = (const int*)  d_in[1];
    const float* ew   = (const float*)d_in[2];
    const int*   mask = (const int*)  d_in[3];
    const float* W1   = (const float*)d_in[4];
    const float* b1   = (const float*)d_in[5];
    const float* W2   = (const float*)d_in[6];
    const float* b2   = (const float*)d_in[7];
    const float* W3   = (const float*)d_in[8];
    const float* b3   = (const float*)d_in[9];
    float* out = (float*)d_out;

    // Workspace layout (~89 MB):
    char* ws = (char*)d_ws;
    _Float16* X16  = (_Float16*)ws;                                   // 16 MB
    _Float16* H16  = (_Float16*)(ws + (16u << 20));                   // 32 MB
    _Float16* Act  = (_Float16*)(ws + (48u << 20));                   // 32 MB
    unsigned int* bkt = (unsigned int*)(ws + (80u << 20));            // 4 MB
    _Float16* Wt1  = (_Float16*)(ws + (84u << 20));                   // 64 KB
    _Float16* Wt2  = Wt1 + 128 * 256;                                 // 128 KB
    _Float16* Wt3  = Wt2 + 256 * 256;                                 // 64 KB
    int* counts    = (int*)(Wt3 + 256 * 128);
    int* row_start = counts + BATCH * NNODE;
    int* cursor    = row_start + BATCH * (NNODE + 1);

    const dim3 blk(256);
    const int edgeBlocks   = BATCH * NEDGE / 256;   // 4096
    const int gatherBlocks = ROWS / 4;              // 16384

    // ---- CSR build (layer-invariant) ----
    hipMemsetAsync(counts, 0, (size_t)BATCH * NNODE * sizeof(int), stream);
    count_kernel<<<edgeBlocks, blk, 0, stream>>>(ei, mask, counts);
    scan_kernel<<<BATCH, blk, 0, stream>>>(counts, row_start, cursor);
    fill_kernel<<<edgeBlocks, blk, 0, stream>>>(ei, ew, mask, cursor, bkt);

    // ---- dtype prep ----
    cast_x_kernel<<<(ROWS * 128 / 4 + 255) / 256, blk, 0, stream>>>(x, X16, ROWS * 128 / 4);
    wt_kernel<<<(128 * 256 + 255) / 256, blk, 0, stream>>>(W1, Wt1, 128, 256);
    wt_kernel<<<(256 * 256 + 255) / 256, blk, 0, stream>>>(W2, Wt2, 256, 256);
    wt_kernel<<<(256 * 128 + 255) / 256, blk, 0, stream>>>(W3, Wt3, 256, 128);

    // ---- Layer 1: 128 -> 256 ----
    gemm_mfma<128><<<dim3(2, ROWS / 128), blk, 0, stream>>>(X16, Wt1, H16, 256);
    gather_kernel<256, _Float16><<<gatherBlocks, blk, 0, stream>>>(row_start, bkt, H16, mask, b1, Act);

    // ---- Layer 2: 256 -> 256 ----
    gemm_mfma<256><<<dim3(2, ROWS / 128), blk, 0, stream>>>(Act, Wt2, H16, 256);
    gather_kernel<256, _Float16><<<gatherBlocks, blk, 0, stream>>>(row_start, bkt, H16, mask, b2, Act);

    // ---- Layer 3: 256 -> 128 ----
    gemm_mfma<256><<<dim3(1, ROWS / 128), blk, 0, stream>>>(Act, Wt3, H16, 128);
    gather_kernel<128, float><<<gatherBlocks, blk, 0, stream>>>(row_start, bkt, H16, mask, b3, out);
}